// Round 1
// 892.718 us; speedup vs baseline: 1.2562x; 1.2562x over previous
//
#include <hip/hip_runtime.h>
#include <cstddef>

// NLM: h=7/255, template 7x7 (TH=3), search 21x21 (SH=10), reflect padding.
// Tile 32x32/block, 256 threads.
// R4: software-pipelined two-stage with DISJOINT wave roles + double-buffered
// vsh, ONE barrier per offset (was two):
//   Bv (tid 0..113 = 38 cols x 3 groups of ~11 rows, waves 0-1): produces
//       vertical 7-sums of d=(u-shifted)^2 for offset i into vsh[i&1].
//       Fast path (blockIdx.y not at image top/bottom): single address reg,
//       17 ds_reads at compile-time row offsets i*XSTR (reflect-stored xs
//       makes xs[a + i*XSTR] exact even when the SEARCH window folds; only
//       folding of patch-center rows breaks linearity -> slow path keeps
//       17 separate addresses, blockIdx.y in {0, 31} only).
//   C  (tid 128..255 = 32 rows x 4 groups of 8 cols, waves 2-3): consumes
//       offset i-1 from vsh[(i-1)&1] concurrently: horizontal 7-sum sliding,
//       8x exp2 weights, shifted-center sliding window, accumulate.
// No wave executes both bodies; Bv and C overlap fully within an iteration.
// R2 lesson kept: no unrolling of the offset loop.

constexpr int TS    = 32;
constexpr int XSTR  = 61;            // odd -> benign bank aliasing
constexpr int XROWS = 59;            // image rows gy0-13 .. gy0+45
constexpr int XSZ   = XROWS * XSTR;  // 3599
constexpr int VSTR  = 42;            // even (float2-aligned), 42%8!=0
constexpr int VROWS = 33;            // 32 + 1 junk row (group-2 uniform writes)
constexpr int VS_SZ = VROWS * VSTR;  // 1386 per buffer (even -> float2 ok)

__device__ __forceinline__ int refl(int i, int n) {
    i = (i < 0) ? -i : i;
    return (i >= n) ? (2 * n - 2 - i) : i;
}

template<bool FASTROWS>
__device__ __forceinline__ void nlm_body(const float* __restrict__ img,
                                         float* __restrict__ out,
                                         int H, int W, int gx0, int gy0,
                                         float* xs, float* vsh, int tid)
{
    // ---- load xs (clip to [0,1], reflect indexing) ----
    for (int e = tid; e < XSZ; e += 256) {
        int i = e / XSTR, j = e - i * XSTR;
        int jj = (j > 57) ? 57 : j;  // cols 58..60: stride pad (never read)
        int gy = refl(gy0 - 13 + i, H);
        int gx = refl(gx0 - 13 + jj, W);
        float v = img[(size_t)gy * W + gx];
        xs[e] = fminf(fmaxf(v, 0.0f), 1.0f);
    }
    __syncthreads();

    // ---- Bv setup: 38 cols x 3 row-groups (rows g*11..g*11+10, 17 q's) ----
    const bool bv = (tid < 114);
    float u[17];
    int   aS[17];
    int   aB = 0;
    int   wb;
    {
        int t  = bv ? tid : 0;
        int g  = t / 38;                 // 0..2
        int cc = t - g * 38;             // 0..37
        int r  = g * 11;                 // first output row of this group
        int mxm10 = refl(gx0 + cc - 3, W) - gx0 + 3;   // mx - 10
        if (FASTROWS) {
            aB = r * XSTR + mxm10;
#pragma unroll
            for (int i = 0; i < 17; ++i)
                u[i] = xs[(r + i + 10) * XSTR + mxm10 + 10];
        } else {
#pragma unroll
            for (int i = 0; i < 17; ++i) {
                int my = refl(gy0 + r + i - 3, H) - gy0 + 13;
                u[i]  = xs[my * XSTR + mxm10 + 10];
                aS[i] = (my - 10) * XSTR + mxm10;
            }
        }
        wb = r * VSTR + cc;
    }

    // ---- C setup ----
    const bool cact = (tid >= 128);
    const int ct = cact ? (tid - 128) : 0;
    const int py = ct >> 2;
    const int c8 = (ct & 3) * 8;
    const int vb = py * VSTR + c8;              // float2-aligned (even)
    int svC = (py + 3) * XSTR + (c8 + 3);       // row base, advances per oy

    int oxB = 0;                                 // uniform ox state machines
    int oxC = 0;

    float p[7];
    float ws[8], ac[8];
#pragma unroll
    for (int k = 0; k < 8; ++k) { ws[k] = 0.f; ac[k] = 0.f; }
    // w = exp(-mean49(d)/H2) = exp2(K * sum49(d))
    const float K = -(65025.0f / 2401.0f) * 1.4426950408889634f;

    auto bv_step = [&](int buf) {
        if (bv) {
            float* vo = vsh + buf * VS_SZ + wb;
            float q[17];
#pragma unroll
            for (int i = 0; i < 17; ++i) {
                float sh = FASTROWS ? xs[aB + i * XSTR] : xs[aS[i]];
                float d  = u[i] - sh;
                q[i] = d * d;
            }
            float s = ((q[0] + q[1]) + (q[2] + q[3])) + ((q[4] + q[5]) + q[6]);
            vo[0] = s;
#pragma unroll
            for (int k = 1; k < 11; ++k) {
                s += q[k + 6] - q[k - 1];
                vo[k * VSTR] = s;      // group 2 row 32 = junk, never read
            }
            int step = (oxB == 20) ? (XSTR - 20) : 1;
            if (FASTROWS) {
                aB += step;
            } else {
#pragma unroll
                for (int i = 0; i < 17; ++i) aS[i] += step;
            }
        }
        oxB = (oxB == 20) ? 0 : oxB + 1;
    };

    auto c_step = [&](int buf) {
        if (cact) {
            if (oxC == 0) {
#pragma unroll
                for (int k = 0; k < 7; ++k) p[k] = xs[svC + k];
            }
            const float2* vp =
                reinterpret_cast<const float2*>(vsh + buf * VS_SZ + vb);
            float2 tA = vp[0], tB = vp[1], tC = vp[2], tD = vp[3];
            float2 tE = vp[4], tF = vp[5], tG = vp[6];
            float p7 = xs[svC + 7 + oxC];
            float h0 = ((tA.x + tA.y) + (tB.x + tB.y)) + ((tC.x + tC.y) + tD.x);
            float h1 = h0 - tA.x + tD.y;
            float h2 = h1 - tA.y + tE.x;
            float h3 = h2 - tB.x + tE.y;
            float h4 = h3 - tB.y + tF.x;
            float h5 = h4 - tC.x + tF.y;
            float h6 = h5 - tC.y + tG.x;
            float h7 = h6 - tD.x + tG.y;
            float w;
            w = __builtin_amdgcn_exp2f(h0 * K); ws[0] += w; ac[0] = fmaf(w, p[0], ac[0]);
            w = __builtin_amdgcn_exp2f(h1 * K); ws[1] += w; ac[1] = fmaf(w, p[1], ac[1]);
            w = __builtin_amdgcn_exp2f(h2 * K); ws[2] += w; ac[2] = fmaf(w, p[2], ac[2]);
            w = __builtin_amdgcn_exp2f(h3 * K); ws[3] += w; ac[3] = fmaf(w, p[3], ac[3]);
            w = __builtin_amdgcn_exp2f(h4 * K); ws[4] += w; ac[4] = fmaf(w, p[4], ac[4]);
            w = __builtin_amdgcn_exp2f(h5 * K); ws[5] += w; ac[5] = fmaf(w, p[5], ac[5]);
            w = __builtin_amdgcn_exp2f(h6 * K); ws[6] += w; ac[6] = fmaf(w, p[6], ac[6]);
            w = __builtin_amdgcn_exp2f(h7 * K); ws[7] += w; ac[7] = fmaf(w, p7,   ac[7]);
#pragma unroll
            for (int k = 0; k < 6; ++k) p[k] = p[k + 1];
            p[6] = p7;
        }
        if (oxC == 20) { oxC = 0; svC += XSTR; } else { ++oxC; }
    };

    // ---- pipelined offset loop: Bv(i) || C(i-1), 1 barrier/iter ----
    bv_step(0);
    __syncthreads();
#pragma unroll 1
    for (int i = 1; i < 441; ++i) {
        bv_step(i & 1);
        c_step(1 - (i & 1));
        __syncthreads();
        // barrier fences: C's reads of buf (i-1)&1 from next iter's Bv writes
        // to that same buffer, and Bv's writes of buf i&1 from next iter's
        // C reads of it.
    }
    c_step(0);   // offset 440 lives in buffer 0

    if (cact) {
        float4 oA, oB;
        oA.x = fminf(fmaxf(ac[0] * __builtin_amdgcn_rcpf(ws[0]), 0.f), 1.f);
        oA.y = fminf(fmaxf(ac[1] * __builtin_amdgcn_rcpf(ws[1]), 0.f), 1.f);
        oA.z = fminf(fmaxf(ac[2] * __builtin_amdgcn_rcpf(ws[2]), 0.f), 1.f);
        oA.w = fminf(fmaxf(ac[3] * __builtin_amdgcn_rcpf(ws[3]), 0.f), 1.f);
        oB.x = fminf(fmaxf(ac[4] * __builtin_amdgcn_rcpf(ws[4]), 0.f), 1.f);
        oB.y = fminf(fmaxf(ac[5] * __builtin_amdgcn_rcpf(ws[5]), 0.f), 1.f);
        oB.z = fminf(fmaxf(ac[6] * __builtin_amdgcn_rcpf(ws[6]), 0.f), 1.f);
        oB.w = fminf(fmaxf(ac[7] * __builtin_amdgcn_rcpf(ws[7]), 0.f), 1.f);
        float* op = &out[((size_t)blockIdx.z * H + (gy0 + py)) * W + (gx0 + c8)];
        *reinterpret_cast<float4*>(op)     = oA;
        *reinterpret_cast<float4*>(op + 4) = oB;
    }
}

__global__ __launch_bounds__(256)
void nlm_kernel(const float* __restrict__ img_all, float* __restrict__ out,
                int H, int W) {
    __shared__ float xs[XSZ];
    __shared__ float vsh[2 * VS_SZ];
    const int tid = threadIdx.x;
    const int gx0 = blockIdx.x * TS;
    const int gy0 = blockIdx.y * TS;
    const float* img = img_all + (size_t)blockIdx.z * H * W;
    // Fast rows iff no patch-center row (gy0-3 .. gy0+35) folds at an edge.
    if (gy0 - 3 >= 0 && gy0 + 35 < H)
        nlm_body<true>(img, out, H, W, gx0, gy0, xs, vsh, tid);
    else
        nlm_body<false>(img, out, H, W, gx0, gy0, xs, vsh, tid);
}

extern "C" void kernel_launch(void* const* d_in, const int* in_sizes, int n_in,
                              void* d_out, int out_size, void* d_ws, size_t ws_size,
                              hipStream_t stream) {
    const float* x = (const float*)d_in[0];
    float* out = (float*)d_out;
    const int H = 1024, W = 1024;
    const int B = in_sizes[0] / (H * W);
    dim3 grid(W / TS, H / TS, B);
    nlm_kernel<<<grid, dim3(256), 0, stream>>>(x, out, H, W);
}